// Round 8
// baseline (156.999 us; speedup 1.0000x reference)
//
#include <hip/hip_runtime.h>

#define N_VARS 50000
#define N_TX   200000
#define DSZ    32

#define NWAVES 4000          // single resident batch (16 waves/CU x 256 CU)
#define NQUAD  12            // quad-steps per wave (4 edges each)
// per wave: 12 quads (48 edges) + 1 final pair (2 edges) = 50 edges; x4000 = 200000

typedef float f32x4 __attribute__((ext_vector_type(4)));

// out = theta (residual initialization), one float4 per thread, single pass
__global__ void copy_theta_kernel(const float4* __restrict__ theta,
                                  float4* __restrict__ out, int n4) {
    int i = blockIdx.x * blockDim.x + threadIdx.x;
    if (i < n4) out[i] = theta[i];
}

// Lane l covers W flat float4 at lane*4 within each 1KiB quarter:
//   row i = it*8 + (l>>3), cols j0 = (l&7)*4.
// W/bias loads NONTEMPORAL (R5 A/B: removing nt cost +18us).
// Value-splitting butterfly (7 shfl per pair): lane l ends holding the dot for
// edge (l&4 ? B : A), row (l&3)*8 + (l>>3).
// Quad body = 2 pairs (4 edges, ~17KB in flight) for deeper MLP.
__global__ __launch_bounds__(256)
void transform_scatter_kernel(const float* __restrict__ theta,
                              const float* __restrict__ W,
                              const float* __restrict__ bia,
                              const int* __restrict__ src,
                              const int* __restrict__ tgt,
                              float* __restrict__ out) {
    const int lane = threadIdx.x & 63;
    const int wave = (blockIdx.x * blockDim.x + threadIdx.x) >> 6;

    const int j0    = (lane & 7) << 2;
    const int g     = lane >> 3;
    const int myRow = (lane & 3) * 8 + g;
    const int hiB   = (lane >> 2) & 1;

    const bool b0 = (lane & 1) != 0;
    const bool b1 = (lane & 2) != 0;
    const bool b2 = (lane & 4) != 0;

    // ---- one pair (2 edges) starting at edge e: load, dot, reduce, scatter ----
    auto do_pair = [&](int e) {
        const int2 sp = *reinterpret_cast<const int2*>(src + e);
        const int2 tp = *reinterpret_cast<const int2*>(tgt + e);

        const f32x4 xA = *reinterpret_cast<const f32x4*>(theta + (size_t)sp.x * DSZ + j0);
        const f32x4 xB = *reinterpret_cast<const f32x4*>(theta + (size_t)sp.y * DSZ + j0);

        const f32x4* WA = reinterpret_cast<const f32x4*>(W + (size_t)e * (DSZ * DSZ));
        const f32x4* WB = WA + 256;

        const f32x4 a0 = __builtin_nontemporal_load(WA +   0 + lane);
        const f32x4 a1 = __builtin_nontemporal_load(WA +  64 + lane);
        const f32x4 a2 = __builtin_nontemporal_load(WA + 128 + lane);
        const f32x4 a3 = __builtin_nontemporal_load(WA + 192 + lane);
        const f32x4 c0 = __builtin_nontemporal_load(WB +   0 + lane);
        const f32x4 c1 = __builtin_nontemporal_load(WB +  64 + lane);
        const f32x4 c2 = __builtin_nontemporal_load(WB + 128 + lane);
        const f32x4 c3 = __builtin_nontemporal_load(WB + 192 + lane);

        const float biasv =
            __builtin_nontemporal_load(bia + ((size_t)e + hiB) * DSZ + myRow);

        float pA0 = a0.x * xA.x + a0.y * xA.y + a0.z * xA.z + a0.w * xA.w;
        float pA1 = a1.x * xA.x + a1.y * xA.y + a1.z * xA.z + a1.w * xA.w;
        float pA2 = a2.x * xA.x + a2.y * xA.y + a2.z * xA.z + a2.w * xA.w;
        float pA3 = a3.x * xA.x + a3.y * xA.y + a3.z * xA.z + a3.w * xA.w;
        float pB0 = c0.x * xB.x + c0.y * xB.y + c0.z * xB.z + c0.w * xB.w;
        float pB1 = c1.x * xB.x + c1.y * xB.y + c1.z * xB.z + c1.w * xB.w;
        float pB2 = c2.x * xB.x + c2.y * xB.y + c2.z * xB.z + c2.w * xB.w;
        float pB3 = c3.x * xB.x + c3.y * xB.y + c3.z * xB.z + c3.w * xB.w;

        float vA01 = b0 ? pA1 : pA0, oA01 = b0 ? pA0 : pA1;
        float vA23 = b0 ? pA3 : pA2, oA23 = b0 ? pA2 : pA3;
        float vB01 = b0 ? pB1 : pB0, oB01 = b0 ? pB0 : pB1;
        float vB23 = b0 ? pB3 : pB2, oB23 = b0 ? pB2 : pB3;
        vA01 += __shfl_xor(oA01, 1);
        vA23 += __shfl_xor(oA23, 1);
        vB01 += __shfl_xor(oB01, 1);
        vB23 += __shfl_xor(oB23, 1);

        float vA = b1 ? vA23 : vA01, oA = b1 ? vA01 : vA23;
        float vB = b1 ? vB23 : vB01, oB = b1 ? vB01 : vB23;
        vA += __shfl_xor(oA, 2);
        vB += __shfl_xor(oB, 2);

        float v = b2 ? vB : vA, o = b2 ? vA : vB;
        v += __shfl_xor(o, 4);

        const int te = b2 ? tp.y : tp.x;
        atomicAdd(out + (size_t)te * DSZ + myRow, -(v + biasv));
    };

    // 12 quad-steps: wave w's quad q starts at edge 4*(wave + q*NWAVES)
    for (int q = 0; q < NQUAD; ++q) {
        const int e = 4 * (wave + q * NWAVES);
        do_pair(e);
        do_pair(e + 2);
    }
    // final pair-step: edges [4*NQUAD*NWAVES, N_TX), pair index = wave
    do_pair(4 * NQUAD * NWAVES + 2 * wave);
}

extern "C" void kernel_launch(void* const* d_in, const int* in_sizes, int n_in,
                              void* d_out, int out_size, void* d_ws, size_t ws_size,
                              hipStream_t stream) {
    const float* theta = (const float*)d_in[0];
    const float* W     = (const float*)d_in[1];
    const float* b     = (const float*)d_in[2];
    const int*   src   = (const int*)d_in[3];
    const int*   tgt   = (const int*)d_in[4];
    float* out = (float*)d_out;

    // 1) out = theta (single pass)
    const int n4 = (N_VARS * DSZ) / 4;
    copy_theta_kernel<<<(n4 + 255) / 256, 256, 0, stream>>>(
        (const float4*)theta, (float4*)out, n4);

    // 2) scatter transforms: 4000 waves, quad-granularity sliding window
    transform_scatter_kernel<<<NWAVES / 4, 256, 0, stream>>>(theta, W, b, src, tgt, out);
}